// Round 9
// baseline (190.581 us; speedup 1.0000x reference)
//
#include <hip/hip_runtime.h>
#include <hip/hip_bf16.h>
#include <math.h>

#define GLOBAL_AS __attribute__((address_space(1)))
#define LDS_AS __attribute__((address_space(3)))

typedef __bf16 bf16x8 __attribute__((ext_vector_type(8)));
typedef __bf16 bf16x4 __attribute__((ext_vector_type(4)));
typedef float f32x4 __attribute__((ext_vector_type(4)));
typedef float f32x16 __attribute__((ext_vector_type(16)));
typedef unsigned short u16x8 __attribute__((ext_vector_type(8)));

static constexpr int BB = 4, SS = 2048, DD = 1024, HH = 16, DKK = 64;
static constexpr int MM = BB * SS;      // 8192 rows
static constexpr int NQKV = 3 * DD;     // 3072
static constexpr int NQT = SS / 128;    // 16 q-tiles

__device__ inline unsigned int cvt_pk_bf16(float lo, float hi) {
  unsigned int r;
  asm("v_cvt_pk_bf16_f32 %0, %1, %2" : "=v"(r) : "v"(lo), "v"(hi));
  return r;
}

// ---------------- fp32 -> bf16 convert (x) ----------------
__global__ __launch_bounds__(256) void cvt_kernel(const float* __restrict__ in,
                                                  __bf16* __restrict__ out,
                                                  int n4) {
  int i = blockIdx.x * blockDim.x + threadIdx.x;
  if (i < n4) {
    float4 v = reinterpret_cast<const float4*>(in)[i];
    bf16x4 o;
    o[0] = (__bf16)v.x; o[1] = (__bf16)v.y; o[2] = (__bf16)v.z; o[3] = (__bf16)v.w;
    *reinterpret_cast<bf16x4*>(out + (size_t)i * 4) = o;
  }
}

// ---------------- merged weight converts ----------------
__global__ __launch_bounds__(256) void cvtw_kernel(const float* __restrict__ w_q,
                                                   const float* __restrict__ w_k,
                                                   const float* __restrict__ w_v,
                                                   const float* __restrict__ w_o,
                                                   __bf16* __restrict__ w_qkv,
                                                   __bf16* __restrict__ w_obf) {
  const int sel = blockIdx.y;
  const float* src = (sel == 0) ? w_q : (sel == 1) ? w_k : (sel == 2) ? w_v : w_o;
  __bf16* dst = (sel < 3) ? (w_qkv + (size_t)sel * DD * DD) : w_obf;
  int i = blockIdx.x * blockDim.x + threadIdx.x;
  float4 v = reinterpret_cast<const float4*>(src)[i];
  bf16x4 o;
  o[0] = (__bf16)v.x; o[1] = (__bf16)v.y; o[2] = (__bf16)v.z; o[3] = (__bf16)v.w;
  *reinterpret_cast<bf16x4*>(dst + (size_t)i * 4) = o;
}

// ================= 256x256 8-phase NT GEMM (QKV projection) =================
// C[M,N] = A[M,K]*B[N,K]^T. 8 waves (2M x 4N), wave tile 128x64, BK=64.
// LDS 128KB: SA/SB[buf][half:128 rows][128x64 shorts], swizzle chunk^=(row&7).
// Quarter-tile (64-row) staging via global_load_lds, counted vmcnt (4/2/4/2),
// quadrant order (r0c0)(r0c1)(r1c1)(r1c0), A/B frags register-cached.
// Epilogue: Q cols scaled by 0.125*log2(e); V cols written transposed to vt.
__global__ __launch_bounds__(512, 1) void gemm256(const unsigned short* __restrict__ A,
                                                  const unsigned short* __restrict__ Bm,
                                                  unsigned short* __restrict__ qkv,
                                                  unsigned short* __restrict__ vt,
                                                  int Ndim, int K) {
  __shared__ __align__(16) unsigned short SA[2][2][8192];
  __shared__ __align__(16) unsigned short SB[2][2][8192];
  const int tid = threadIdx.x, wid = tid >> 6, ln = tid & 63;
  const int wm = wid >> 2, wn = wid & 3;
  const int cl = ln & 15, ck = ln >> 4;

  const int gx = gridDim.x, nwg = gx * gridDim.y;
  const int qch = nwg >> 3;
  int lid = blockIdx.y * gx + blockIdx.x;
  lid = (lid & 7) * qch + (lid >> 3);
  const int bn0 = (lid % gx) * 256;
  const int bm0 = (lid / gx) * 256;

  const int KT = K >> 6;
  const int srow = tid >> 3;
  const int scol8 = (((tid & 7) ^ (srow & 7)) << 3);   // pre-swizzled source chunk
  int chk[2];
  chk[0] = ((ck ^ (cl & 7)) << 3);                     // swizzled read chunks
  chk[1] = (((4 + ck) ^ (cl & 7)) << 3);

  f32x4 acc[8][4] = {};
  bf16x8 aR[4][2], bRa[2][2], bRb[2][2];

  auto stA = [&](int t, int qa) {   // stage A quarter (rows qa*64..+63), 1 load/thread
    const unsigned short* g = A + (size_t)(bm0 + qa * 64 + srow) * K + t * 64 + scol8;
    __builtin_amdgcn_global_load_lds((GLOBAL_AS void*)g,
        (LDS_AS void*)(&SA[t & 1][qa >> 1][(qa & 1) * 4096 + tid * 8]), 16, 0, 0);
  };
  auto stB = [&](int t, int qb) {
    const unsigned short* g = Bm + (size_t)(bn0 + qb * 64 + srow) * K + t * 64 + scol8;
    __builtin_amdgcn_global_load_lds((GLOBAL_AS void*)g,
        (LDS_AS void*)(&SB[t & 1][qb >> 1][(qb & 1) * 4096 + tid * 8]), 16, 0, 0);
  };
  auto ldA = [&](int buf, int rh) {
    const unsigned short* base = &SA[buf][wm][0];
#pragma unroll
    for (int rf = 0; rf < 4; ++rf) {
      const int row = rh * 64 + rf * 16 + cl;
#pragma unroll
      for (int kk = 0; kk < 2; ++kk)
        aR[rf][kk] = *reinterpret_cast<const bf16x8*>(base + row * 64 + chk[kk]);
    }
  };
  auto ldB = [&](int buf, int chalf, bf16x8 (&br)[2][2]) {
    const unsigned short* base = &SB[buf][wn >> 1][0];
#pragma unroll
    for (int cf = 0; cf < 2; ++cf) {
      const int row = (wn & 1) * 64 + chalf * 32 + cf * 16 + cl;
#pragma unroll
      for (int kk = 0; kk < 2; ++kk)
        br[cf][kk] = *reinterpret_cast<const bf16x8*>(base + row * 64 + chk[kk]);
    }
  };
  auto MF = [&](int rh, int chalf, bf16x8 (&br)[2][2]) {
    __builtin_amdgcn_s_setprio(1);
#pragma unroll
    for (int rf = 0; rf < 4; ++rf)
#pragma unroll
      for (int cf = 0; cf < 2; ++cf)
#pragma unroll
        for (int kk = 0; kk < 2; ++kk)
          acc[rh * 4 + rf][chalf * 2 + cf] = __builtin_amdgcn_mfma_f32_16x16x32_bf16(
              aR[rf][kk], br[cf][kk], acc[rh * 4 + rf][chalf * 2 + cf], 0, 0, 0);
    __builtin_amdgcn_s_setprio(0);
  };

  // prologue: tile 0 in steady-state order (B0..B3, A0,A2, A1,A3)
  stB(0, 0); stB(0, 1); stB(0, 2); stB(0, 3);
  stA(0, 0); stA(0, 2); stA(0, 1); stA(0, 3);
  asm volatile("s_waitcnt vmcnt(2)" ::: "memory");
  __builtin_amdgcn_s_barrier();

  const int HKT = KT >> 1;
  for (int it = 0; it < HKT; ++it) {
    const int t1 = 2 * it + 1, v = 2 * it + 2;
    const bool hv = (v < KT);
    // ---- ph1: t0 (r0,c0); stage t1.B0,B1 ----
    ldA(0, 0); ldB(0, 0, bRa);
    stB(t1, 0); stB(t1, 1);
    __builtin_amdgcn_s_barrier();
    MF(0, 0, bRa);
    __builtin_amdgcn_s_barrier();
    // ---- ph2: t0 (r0,c1); stage t1.B2,B3; vmcnt(4) ----
    ldB(0, 1, bRb);
    stB(t1, 2); stB(t1, 3);
    __builtin_amdgcn_s_barrier();
    MF(0, 1, bRb);
    asm volatile("s_waitcnt vmcnt(4)" ::: "memory");
    __builtin_amdgcn_s_barrier();
    // ---- ph3: t0 (r1,c1); stage t1.A0,A2 ----
    ldA(0, 1);
    stA(t1, 0); stA(t1, 2);
    __builtin_amdgcn_s_barrier();
    MF(1, 1, bRb);
    __builtin_amdgcn_s_barrier();
    // ---- ph4: t0 (r1,c0); stage t1.A1,A3; vmcnt(2) ----
    stA(t1, 1); stA(t1, 3);
    __builtin_amdgcn_s_barrier();
    MF(1, 0, bRa);
    asm volatile("s_waitcnt vmcnt(2)" ::: "memory");
    __builtin_amdgcn_s_barrier();
    // ---- ph5: t1 (r0,c0); stage v.B0,B1 ----
    ldA(1, 0); ldB(1, 0, bRa);
    if (hv) { stB(v, 0); stB(v, 1); }
    __builtin_amdgcn_s_barrier();
    MF(0, 0, bRa);
    __builtin_amdgcn_s_barrier();
    // ---- ph6: t1 (r0,c1); stage v.B2,B3; vmcnt ----
    ldB(1, 1, bRb);
    if (hv) { stB(v, 2); stB(v, 3); }
    __builtin_amdgcn_s_barrier();
    MF(0, 1, bRb);
    if (hv) asm volatile("s_waitcnt vmcnt(4)" ::: "memory");
    else    asm volatile("s_waitcnt vmcnt(0)" ::: "memory");
    __builtin_amdgcn_s_barrier();
    // ---- ph7: t1 (r1,c1); stage v.A0,A2 ----
    ldA(1, 1);
    if (hv) { stA(v, 0); stA(v, 2); }
    __builtin_amdgcn_s_barrier();
    MF(1, 1, bRb);
    __builtin_amdgcn_s_barrier();
    // ---- ph8: t1 (r1,c0); stage v.A1,A3; vmcnt(2) ----
    if (hv) { stA(v, 1); stA(v, 3); }
    __builtin_amdgcn_s_barrier();
    MF(1, 0, bRa);
    if (hv) asm volatile("s_waitcnt vmcnt(2)" ::: "memory");
    __builtin_amdgcn_s_barrier();
  }

  // ---- epilogue: Q-scale cols<DD; V cols>=2*DD transposed into vt ----
#pragma unroll
  for (int rf8 = 0; rf8 < 8; ++rf8) {
#pragma unroll
    for (int cf4 = 0; cf4 < 4; ++cf4) {
      const int col = bn0 + wn * 64 + cf4 * 16 + cl;
      const int row0 = bm0 + wm * 128 + rf8 * 16 + ck * 4;
      if (col >= 2 * DD) {
        const int hcol = col - 2 * DD;
        const int hh = hcol >> 6, dk = hcol & 63;
        const int bb_ = row0 >> 11, s0 = row0 & 2047;
        bf16x4 pv;
#pragma unroll
        for (int r = 0; r < 4; ++r) pv[r] = (__bf16)acc[rf8][cf4][r];
        *reinterpret_cast<bf16x4*>(vt + ((size_t)((bb_ * HH + hh) * 64 + dk)) * SS + s0) = pv;
      } else {
#pragma unroll
        for (int r = 0; r < 4; ++r) {
          float vv = acc[rf8][cf4][r];
          if (col < DD) vv *= 0.18033688011112042f;  // 0.125*log2(e)
          ((__bf16*)qkv)[(size_t)(row0 + r) * Ndim + col] = (__bf16)vv;
        }
      }
    }
  }
}

// ---------------- phase-pipelined NT GEMM (out-projection, f32 out + bias) ----------------
__global__ __launch_bounds__(512, 1) void gemm8p(const unsigned short* __restrict__ A,
                                                 const unsigned short* __restrict__ Bm,
                                                 float* __restrict__ Cout,
                                                 const float* __restrict__ bias,
                                                 int Ndim, int K) {
  __shared__ __align__(16) unsigned short Asm[2 * 2 * 4096];   // [buf][kk][128*32]
  __shared__ __align__(16) unsigned short Bsm[2 * 2 * 8192];   // [buf][kk][256*32]
  const int tid = threadIdx.x, wid = tid >> 6, ln = tid & 63;
  const int wm = wid >> 2, wn = wid & 3;
  const int cl = ln & 15, ck = ln >> 4;

  const int gx = gridDim.x;
  const int nwg = gx * gridDim.y;
  const int qch = nwg >> 3;
  int lid = blockIdx.y * gx + blockIdx.x;
  lid = (lid & 7) * qch + (lid >> 3);
  const int bn0 = (lid % gx) * 256;
  const int bm0 = (lid / gx) * 128;

  const int KT = K >> 6;
  const int sr = tid >> 2;
  const int scol = ((tid & 3) ^ (sr & 3)) << 3;
  const int sc8 = (ck ^ (cl & 3)) << 3;

  f32x4 acc[4][4] = {};

  auto stage_group = [&](int buf, int kt, int kk) {
    const int k0 = kt * 64 + kk * 32;
    const unsigned short* ga = A + (size_t)(bm0 + sr) * K + k0 + scol;
    __builtin_amdgcn_global_load_lds((GLOBAL_AS void*)ga,
        (LDS_AS void*)(Asm + (buf * 2 + kk) * 4096 + wid * 512), 16, 0, 0);
#pragma unroll
    for (int j = 0; j < 2; ++j) {
      const unsigned short* gb = Bm + (size_t)(bn0 + j * 128 + sr) * K + k0 + scol;
      __builtin_amdgcn_global_load_lds((GLOBAL_AS void*)gb,
          (LDS_AS void*)(Bsm + (buf * 2 + kk) * 8192 + j * 4096 + wid * 512), 16, 0, 0);
    }
  };

  auto phase = [&](int p, int kk, int g_buf, int g_kt, int g_kk, bool g_issue, int vm) {
    bf16x8 af[4], bfr[4];
    const unsigned short* ab = Asm + (p * 2 + kk) * 4096;
    const unsigned short* bb = Bsm + (p * 2 + kk) * 8192;
#pragma unroll
    for (int mf = 0; mf < 4; ++mf)
      af[mf] = *reinterpret_cast<const bf16x8*>(ab + (wm * 64 + mf * 16 + cl) * 32 + sc8);
#pragma unroll
    for (int nf = 0; nf < 4; ++nf)
      bfr[nf] = *reinterpret_cast<const bf16x8*>(bb + (wn * 64 + nf * 16 + cl) * 32 + sc8);
    if (g_issue) stage_group(g_buf, g_kt, g_kk);
    __builtin_amdgcn_s_barrier();
    __builtin_amdgcn_s_setprio(1);
#pragma unroll
    for (int mf = 0; mf < 4; ++mf)
#pragma unroll
      for (int nf = 0; nf < 4; ++nf)
        acc[mf][nf] = __builtin_amdgcn_mfma_f32_16x16x32_bf16(af[mf], bfr[nf], acc[mf][nf], 0, 0, 0);
    __builtin_amdgcn_s_setprio(0);
    if (vm == 6)      asm volatile("s_waitcnt vmcnt(6)" ::: "memory");
    else if (vm == 3) asm volatile("s_waitcnt vmcnt(3)" ::: "memory");
    else if (vm == 0) asm volatile("s_waitcnt vmcnt(0)" ::: "memory");
    __builtin_amdgcn_s_barrier();
  };

  stage_group(0, 0, 0);
  stage_group(0, 0, 1);
  stage_group(1, 1, 0);
  asm volatile("s_waitcnt vmcnt(6)" ::: "memory");
  __builtin_amdgcn_s_barrier();

  for (int kt = 0; kt < KT; ++kt) {
    const int p = kt & 1;
    const bool i0 = (kt + 1 < KT);
    const bool i1 = (kt + 2 < KT);
    phase(p, 0, p ^ 1, kt + 1, 1, i0, i0 ? 6 : 0);
    phase(p, 1, p, kt + 2, 0, i1, (kt < KT - 1) ? (i1 ? 6 : 3) : -1);
  }

#pragma unroll
  for (int mf = 0; mf < 4; ++mf) {
#pragma unroll
    for (int nf = 0; nf < 4; ++nf) {
      const int col = bn0 + wn * 64 + nf * 16 + cl;
#pragma unroll
      for (int r = 0; r < 4; ++r) {
        const int row = bm0 + wm * 64 + mf * 16 + ck * 4 + r;
        Cout[(size_t)row * Ndim + col] = acc[mf][nf][r] + bias[col];
      }
    }
  }
}

// ---------------- causal flash attention (swapped-operand 32x32 MFMA, in-register P) ----------------
__global__ __launch_bounds__(256) void attn_kernel(const unsigned short* __restrict__ qkv,
                                                   const unsigned short* __restrict__ vt,
                                                   unsigned short* __restrict__ attn_out) {
  const int pi = blockIdx.x, h = blockIdx.y, b = blockIdx.z;
  const int tid = threadIdx.x, wv = tid >> 6, ln = tid & 63;
  const int l31 = ln & 31, hi = ln >> 5;
  const int bh = b * HH + h;

  __shared__ __align__(16) unsigned short Ks[2][64 * 64];
  __shared__ __align__(16) unsigned short Vs[2][64 * 64];

  bf16x8 vones;
#pragma unroll
  for (int j = 0; j < 8; ++j) vones[j] = (__bf16)1.0f;

  auto stage = [&](int bsel, int kv0s) {
#pragma unroll
    for (int i = 0; i < 2; ++i) {
      int idx = wv * 2 + i;
      int row = idx * 8 + (ln >> 3);
      int sch = (ln & 7) ^ (row & 7);
      const unsigned short* gk = qkv + ((size_t)(b * SS + kv0s + row) * NQKV + DD + h * DKK + sch * 8);
      __builtin_amdgcn_global_load_lds((GLOBAL_AS void*)gk, (LDS_AS void*)(&Ks[bsel][idx * 512]), 16, 0, 0);
      const unsigned short* gv = vt + ((size_t)(bh * 64 + row) * SS + kv0s + sch * 8);
      __builtin_amdgcn_global_load_lds((GLOBAL_AS void*)gv, (LDS_AS void*)(&Vs[bsel][idx * 512]), 16, 0, 0);
    }
  };

  auto process = [&](int qt) {
    const int q0w = qt * 128 + wv * 32;
    const int qq = q0w + l31;

    bf16x8 qf[4];
#pragma unroll
    for (int kkk = 0; kkk < 4; ++kkk)
      qf[kkk] = *reinterpret_cast<const bf16x8*>(
          qkv + (size_t)(b * SS + qq) * NQKV + h * DKK + kkk * 16 + hi * 8);

    f32x16 ot[2] = {};
    f32x16 lsum = {};
    float mrow = -INFINITY;

    const int nt = 2 * qt + 2;
    stage(0, 0);
    __syncthreads();
    int buf = 0;

    for (int t = 0; t < nt; ++t) {
      const int kv0 = t * 64;
      if (t + 1 < nt) stage(buf ^ 1, (t + 1) * 64);

      if (kv0 <= q0w + 31) {
        const unsigned short* kb = &Ks[buf][0];
        const unsigned short* vb = &Vs[buf][0];

        f32x16 st[2];
        __builtin_amdgcn_s_setprio(1);
#pragma unroll
        for (int cc = 0; cc < 2; ++cc) {
          f32x16 z = {};
#pragma unroll
          for (int kkk = 0; kkk < 4; ++kkk) {
            bf16x8 kf = *reinterpret_cast<const bf16x8*>(
                kb + (cc * 32 + l31) * 64 + (((kkk * 2 + hi) ^ (l31 & 7)) * 8));
            z = __builtin_amdgcn_mfma_f32_32x32x16_bf16(kf, qf[kkk], z, 0, 0, 0);
          }
          st[cc] = z;
        }
        __builtin_amdgcn_s_setprio(0);

        if (kv0 + 63 > q0w) {
          const int kvb = kv0 + 4 * hi;
#pragma unroll
          for (int cc = 0; cc < 2; ++cc)
#pragma unroll
            for (int r = 0; r < 16; ++r) {
              const int kv = kvb + cc * 32 + (r & 3) + 8 * (r >> 2);
              st[cc][r] = (kv <= qq) ? st[cc][r] : -INFINITY;
            }
        }

        float tm = st[0][0];
#pragma unroll
        for (int r = 1; r < 16; ++r) tm = fmaxf(tm, st[0][r]);
#pragma unroll
        for (int r = 0; r < 16; ++r) tm = fmaxf(tm, st[1][r]);
        tm = fmaxf(tm, __shfl_xor(tm, 32));

        if (__any(tm - mrow > 8.0f)) {
          float mn = fmaxf(mrow, tm);
          float al = __builtin_amdgcn_exp2f(mrow - mn);
          mrow = mn;
          lsum *= al;
          ot[0] *= al;
          ot[1] *= al;
        }

#pragma unroll
        for (int cc = 0; cc < 2; ++cc)
#pragma unroll
          for (int r = 0; r < 16; ++r)
            st[cc][r] = __builtin_amdgcn_exp2f(st[cc][r] - mrow);

        unsigned int pk[2][4], pk2[2][4];
#pragma unroll
        for (int cc = 0; cc < 2; ++cc)
#pragma unroll
          for (int g = 0; g < 4; ++g) {
            pk[cc][g]  = cvt_pk_bf16(st[cc][4 * g + 0], st[cc][4 * g + 1]);
            pk2[cc][g] = cvt_pk_bf16(st[cc][4 * g + 2], st[cc][4 * g + 3]);
          }

        __builtin_amdgcn_s_setprio(1);
#pragma unroll
        for (int ks = 0; ks < 4; ++ks) {
          const int cc = ks >> 1, g0 = 2 * (ks & 1), g1 = g0 + 1;
          unsigned int Aw = pk[cc][g0], Bw = pk[cc][g1];
          asm volatile("v_permlane32_swap_b32 %0, %1" : "+v"(Aw), "+v"(Bw));
          unsigned int A2 = pk2[cc][g0], B2 = pk2[cc][g1];
          asm volatile("v_permlane32_swap_b32 %0, %1" : "+v"(A2), "+v"(B2));
          union { unsigned int u[4]; bf16x8 v; } pb;
          pb.u[0] = Aw; pb.u[1] = A2; pb.u[2] = Bw; pb.u[3] = B2;
          lsum = __builtin_amdgcn_mfma_f32_32x32x16_bf16(vones, pb.v, lsum, 0, 0, 0);
#pragma unroll
          for (int dc = 0; dc < 2; ++dc) {
            bf16x8 vf = *reinterpret_cast<const bf16x8*>(
                vb + (dc * 32 + l31) * 64 + (((ks * 2 + hi) ^ (l31 & 7)) * 8));
            ot[dc] = __builtin_amdgcn_mfma_f32_32x32x16_bf16(vf, pb.v, ot[dc], 0, 0, 0);
          }
        }
        __builtin_amdgcn_s_setprio(0);
      }

      __syncthreads();
      buf ^= 1;
    }

    const float inv = 1.0f / lsum[0];
    __bf16* aout = (__bf16*)attn_out + (size_t)(b * SS + qq) * DD + h * DKK;
#pragma unroll
    for (int dc = 0; dc < 2; ++dc)
#pragma unroll
      for (int g = 0; g < 4; ++g) {
        uint2 pw;
        pw.x = cvt_pk_bf16(ot[dc][4 * g + 0] * inv, ot[dc][4 * g + 1] * inv);
        pw.y = cvt_pk_bf16(ot[dc][4 * g + 2] * inv, ot[dc][4 * g + 3] * inv);
        *reinterpret_cast<uint2*>(aout + dc * 32 + 4 * hi + 8 * g) = pw;
      }
  };

  process(NQT - 1 - pi);
  process(pi);
}

// ---------------- launch ----------------
extern "C" void kernel_launch(void* const* d_in, const int* in_sizes, int n_in,
                              void* d_out, int out_size, void* d_ws, size_t ws_size,
                              hipStream_t stream) {
  const float* x = (const float*)d_in[0];
  const float* w_q = (const float*)d_in[1];
  const float* w_k = (const float*)d_in[2];
  const float* w_v = (const float*)d_in[3];
  const float* w_o = (const float*)d_in[4];
  const float* b_o = (const float*)d_in[5];
  float* out = (float*)d_out;

  unsigned short* ws = (unsigned short*)d_ws;
  unsigned short* x_bf = ws;                               // 8192*1024
  unsigned short* w_qkv = x_bf + (size_t)MM * DD;          // 3072*1024
  unsigned short* w_obf = w_qkv + (size_t)NQKV * DD;       // 1024*1024
  unsigned short* qkv = w_obf + (size_t)DD * DD;           // 8192*3072 (V region unused)
  unsigned short* vt = qkv + (size_t)MM * NQKV;            // B*H*DK*S = 8388608
  unsigned short* attn = vt + (size_t)BB * HH * DKK * SS;  // 8192*1024

  // converts
  cvt_kernel<<<(MM * DD / 4 + 255) / 256, 256, 0, stream>>>(x, (__bf16*)x_bf, MM * DD / 4);
  cvtw_kernel<<<dim3(DD * DD / 4 / 256, 4), 256, 0, stream>>>(w_q, w_k, w_v, w_o,
                                                              (__bf16*)w_qkv, (__bf16*)w_obf);

  // QKV projection (256^2 8-phase; Q prescaled; V written transposed into vt)
  gemm256<<<dim3(NQKV / 256, MM / 256), 512, 0, stream>>>(x_bf, w_qkv, qkv, vt, NQKV, DD);

  // attention (pair-balanced causal schedule)
  attn_kernel<<<dim3(NQT / 2, HH, BB), 256, 0, stream>>>(qkv, vt, attn);

  // output projection: [8192,1024] = attn @ w_o^T + b_o
  gemm8p<<<dim3(DD / 256, MM / 128), 512, 0, stream>>>(attn, w_obf, out, b_o, DD, DD);
}

// Round 10
// 166.756 us; speedup vs baseline: 1.1429x; 1.1429x over previous
//
#include <hip/hip_runtime.h>
#include <hip/hip_bf16.h>
#include <math.h>

#define GLOBAL_AS __attribute__((address_space(1)))
#define LDS_AS __attribute__((address_space(3)))

typedef __bf16 bf16x8 __attribute__((ext_vector_type(8)));
typedef __bf16 bf16x4 __attribute__((ext_vector_type(4)));
typedef float f32x4 __attribute__((ext_vector_type(4)));
typedef float f32x16 __attribute__((ext_vector_type(16)));
typedef unsigned short u16x8 __attribute__((ext_vector_type(8)));

static constexpr int BB = 4, SS = 2048, DD = 1024, HH = 16, DKK = 64;
static constexpr int MM = BB * SS;      // 8192 rows
static constexpr int NQKV = 3 * DD;     // 3072
static constexpr int NQT = SS / 128;    // 16 q-tiles

__device__ inline unsigned int cvt_pk_bf16(float lo, float hi) {
  unsigned int r;
  asm("v_cvt_pk_bf16_f32 %0, %1, %2" : "=v"(r) : "v"(lo), "v"(hi));
  return r;
}

// ---------------- fp32 -> bf16 convert (x) ----------------
__global__ __launch_bounds__(256) void cvt_kernel(const float* __restrict__ in,
                                                  __bf16* __restrict__ out,
                                                  int n4) {
  int i = blockIdx.x * blockDim.x + threadIdx.x;
  if (i < n4) {
    float4 v = reinterpret_cast<const float4*>(in)[i];
    bf16x4 o;
    o[0] = (__bf16)v.x; o[1] = (__bf16)v.y; o[2] = (__bf16)v.z; o[3] = (__bf16)v.w;
    *reinterpret_cast<bf16x4*>(out + (size_t)i * 4) = o;
  }
}

// ---------------- merged weight converts ----------------
__global__ __launch_bounds__(256) void cvtw_kernel(const float* __restrict__ w_q,
                                                   const float* __restrict__ w_k,
                                                   const float* __restrict__ w_v,
                                                   const float* __restrict__ w_o,
                                                   __bf16* __restrict__ w_qkv,
                                                   __bf16* __restrict__ w_obf) {
  const int sel = blockIdx.y;
  const float* src = (sel == 0) ? w_q : (sel == 1) ? w_k : (sel == 2) ? w_v : w_o;
  __bf16* dst = (sel < 3) ? (w_qkv + (size_t)sel * DD * DD) : w_obf;
  int i = blockIdx.x * blockDim.x + threadIdx.x;
  float4 v = reinterpret_cast<const float4*>(src)[i];
  bf16x4 o;
  o[0] = (__bf16)v.x; o[1] = (__bf16)v.y; o[2] = (__bf16)v.z; o[3] = (__bf16)v.w;
  *reinterpret_cast<bf16x4*>(dst + (size_t)i * 4) = o;
}

// ================= m97-style 128x128 NT GEMM, 3 blocks/CU =================
// C[M,N] = A[M,K]*B[N,K]^T. 4 waves (2M x 2N), wave tile 64x64, BK=64.
// LDS 32KB single-buffered (SA/SB 128x64), conflict-free XOR swizzle:
// linear LDS dest + pre-swizzled global source col; read chunk = (4kk+ck)^(row&7).
// Cross-block overlap (3 blocks/CU) hides the __syncthreads drain (m114/m103).
// MODE 2: bf16 out; cols<DD scaled by 0.125*log2(e); cols>=2*DD -> vt transposed.
// MODE 0: f32 out + bias.
template <int MODE>
__global__ __launch_bounds__(256, 3) void gemm128(const unsigned short* __restrict__ A,
                                                  const unsigned short* __restrict__ Bm,
                                                  void* __restrict__ Cout,
                                                  const float* __restrict__ bias,
                                                  unsigned short* __restrict__ vt,
                                                  int Ndim, int K) {
  __shared__ __align__(16) unsigned short SA[128 * 64];
  __shared__ __align__(16) unsigned short SB[128 * 64];
  const int tid = threadIdx.x, wv = tid >> 6, ln = tid & 63;
  const int wm = wv >> 1, wn = wv & 1;
  const int cl = ln & 15, ck = ln >> 4;

  // XCD-aware bijective swizzle (nwg % 8 == 0 for all launch configs here)
  const int gx = gridDim.x, nwg = gx * gridDim.y;
  const int qch = nwg >> 3;
  int lid = blockIdx.y * gx + blockIdx.x;
  lid = (lid & 7) * qch + (lid >> 3);
  const int bn0 = (lid % gx) * 128;
  const int bm0 = (lid / gx) * 128;

  const int KT = K >> 6;
  // staging: load i covers rows i*32..i*32+31; LDS dest linear tid*8 within unit;
  // global source col chunk pre-swizzled so LDS[row][c] = global[row][c ^ (row&7)].
  const int sr = tid >> 3;                 // row-within-32 block
  // read chunks: global chunk (4kk+ck) of row r lives at LDS chunk (4kk+ck)^(r&7); r&7==cl&7
  int chk[2];
  chk[0] = ((ck ^ (cl & 7)) << 3);
  chk[1] = (((4 + ck) ^ (cl & 7)) << 3);

  f32x4 acc[4][4] = {};

  for (int kt = 0; kt < KT; ++kt) {
    const int k0 = kt * 64;
#pragma unroll
    for (int i = 0; i < 4; ++i) {
      const int row = i * 32 + sr;
      const int sc = (((tid & 7) ^ (row & 7)) << 3);
      const unsigned short* ga = A + (size_t)(bm0 + row) * K + k0 + sc;
      __builtin_amdgcn_global_load_lds((GLOBAL_AS void*)ga,
          (LDS_AS void*)(SA + i * 2048 + tid * 8), 16, 0, 0);
      const unsigned short* gb = Bm + (size_t)(bn0 + row) * K + k0 + sc;
      __builtin_amdgcn_global_load_lds((GLOBAL_AS void*)gb,
          (LDS_AS void*)(SB + i * 2048 + tid * 8), 16, 0, 0);
    }
    __syncthreads();

    bf16x8 af[4][2], bf[4][2];
#pragma unroll
    for (int mf = 0; mf < 4; ++mf) {
      const int row = wm * 64 + mf * 16 + cl;
#pragma unroll
      for (int kk = 0; kk < 2; ++kk)
        af[mf][kk] = *reinterpret_cast<const bf16x8*>(SA + row * 64 + chk[kk]);
    }
#pragma unroll
    for (int nf = 0; nf < 4; ++nf) {
      const int row = wn * 64 + nf * 16 + cl;
#pragma unroll
      for (int kk = 0; kk < 2; ++kk)
        bf[nf][kk] = *reinterpret_cast<const bf16x8*>(SB + row * 64 + chk[kk]);
    }
    __builtin_amdgcn_s_setprio(1);
#pragma unroll
    for (int mf = 0; mf < 4; ++mf)
#pragma unroll
      for (int nf = 0; nf < 4; ++nf)
#pragma unroll
        for (int kk = 0; kk < 2; ++kk)
          acc[mf][nf] = __builtin_amdgcn_mfma_f32_16x16x32_bf16(af[mf][kk], bf[nf][kk], acc[mf][nf], 0, 0, 0);
    __builtin_amdgcn_s_setprio(0);
    __syncthreads();
  }

  // ---- epilogue ----
#pragma unroll
  for (int mf = 0; mf < 4; ++mf) {
#pragma unroll
    for (int nf = 0; nf < 4; ++nf) {
      const int col = bn0 + wn * 64 + nf * 16 + cl;
      const int row0 = bm0 + wm * 64 + mf * 16 + ck * 4;
      if constexpr (MODE == 2) {
        if (col >= 2 * DD) {   // V part -> vt[b,h,dk,s], packed 8B
          const int hcol = col - 2 * DD;
          const int hh = hcol >> 6, dk = hcol & 63;
          const int bb_ = row0 >> 11, s0 = row0 & 2047;
          bf16x4 pv;
#pragma unroll
          for (int r = 0; r < 4; ++r) pv[r] = (__bf16)acc[mf][nf][r];
          *reinterpret_cast<bf16x4*>(vt + ((size_t)((bb_ * HH + hh) * 64 + dk)) * SS + s0) = pv;
          continue;
        }
      }
#pragma unroll
      for (int r = 0; r < 4; ++r) {
        float v = acc[mf][nf][r];
        if constexpr (MODE == 0) {
          ((float*)Cout)[(size_t)(row0 + r) * Ndim + col] = v + bias[col];
        } else {
          if (col < DD) v *= 0.18033688011112042f;  // 0.125*log2(e)
          ((__bf16*)Cout)[(size_t)(row0 + r) * Ndim + col] = (__bf16)v;
        }
      }
    }
  }
}

// ---------------- causal flash attention (swapped-operand 32x32 MFMA, in-register P) ----------------
__global__ __launch_bounds__(256) void attn_kernel(const unsigned short* __restrict__ qkv,
                                                   const unsigned short* __restrict__ vt,
                                                   unsigned short* __restrict__ attn_out) {
  const int pi = blockIdx.x, h = blockIdx.y, b = blockIdx.z;
  const int tid = threadIdx.x, wv = tid >> 6, ln = tid & 63;
  const int l31 = ln & 31, hi = ln >> 5;
  const int bh = b * HH + h;

  __shared__ __align__(16) unsigned short Ks[2][64 * 64];
  __shared__ __align__(16) unsigned short Vs[2][64 * 64];

  bf16x8 vones;
#pragma unroll
  for (int j = 0; j < 8; ++j) vones[j] = (__bf16)1.0f;

  auto stage = [&](int bsel, int kv0s) {
#pragma unroll
    for (int i = 0; i < 2; ++i) {
      int idx = wv * 2 + i;
      int row = idx * 8 + (ln >> 3);
      int sch = (ln & 7) ^ (row & 7);
      const unsigned short* gk = qkv + ((size_t)(b * SS + kv0s + row) * NQKV + DD + h * DKK + sch * 8);
      __builtin_amdgcn_global_load_lds((GLOBAL_AS void*)gk, (LDS_AS void*)(&Ks[bsel][idx * 512]), 16, 0, 0);
      const unsigned short* gv = vt + ((size_t)(bh * 64 + row) * SS + kv0s + sch * 8);
      __builtin_amdgcn_global_load_lds((GLOBAL_AS void*)gv, (LDS_AS void*)(&Vs[bsel][idx * 512]), 16, 0, 0);
    }
  };

  auto process = [&](int qt) {
    const int q0w = qt * 128 + wv * 32;
    const int qq = q0w + l31;

    bf16x8 qf[4];
#pragma unroll
    for (int kkk = 0; kkk < 4; ++kkk)
      qf[kkk] = *reinterpret_cast<const bf16x8*>(
          qkv + (size_t)(b * SS + qq) * NQKV + h * DKK + kkk * 16 + hi * 8);

    f32x16 ot[2] = {};
    f32x16 lsum = {};
    float mrow = -INFINITY;

    const int nt = 2 * qt + 2;
    stage(0, 0);
    __syncthreads();
    int buf = 0;

    for (int t = 0; t < nt; ++t) {
      const int kv0 = t * 64;
      if (t + 1 < nt) stage(buf ^ 1, (t + 1) * 64);

      if (kv0 <= q0w + 31) {
        const unsigned short* kb = &Ks[buf][0];
        const unsigned short* vb = &Vs[buf][0];

        f32x16 st[2];
        __builtin_amdgcn_s_setprio(1);
#pragma unroll
        for (int cc = 0; cc < 2; ++cc) {
          f32x16 z = {};
#pragma unroll
          for (int kkk = 0; kkk < 4; ++kkk) {
            bf16x8 kf = *reinterpret_cast<const bf16x8*>(
                kb + (cc * 32 + l31) * 64 + (((kkk * 2 + hi) ^ (l31 & 7)) * 8));
            z = __builtin_amdgcn_mfma_f32_32x32x16_bf16(kf, qf[kkk], z, 0, 0, 0);
          }
          st[cc] = z;
        }
        __builtin_amdgcn_s_setprio(0);

        if (kv0 + 63 > q0w) {
          const int kvb = kv0 + 4 * hi;
#pragma unroll
          for (int cc = 0; cc < 2; ++cc)
#pragma unroll
            for (int r = 0; r < 16; ++r) {
              const int kv = kvb + cc * 32 + (r & 3) + 8 * (r >> 2);
              st[cc][r] = (kv <= qq) ? st[cc][r] : -INFINITY;
            }
        }

        float tm = st[0][0];
#pragma unroll
        for (int r = 1; r < 16; ++r) tm = fmaxf(tm, st[0][r]);
#pragma unroll
        for (int r = 0; r < 16; ++r) tm = fmaxf(tm, st[1][r]);
        tm = fmaxf(tm, __shfl_xor(tm, 32));

        if (__any(tm - mrow > 8.0f)) {
          float mn = fmaxf(mrow, tm);
          float al = __builtin_amdgcn_exp2f(mrow - mn);
          mrow = mn;
          lsum *= al;
          ot[0] *= al;
          ot[1] *= al;
        }

#pragma unroll
        for (int cc = 0; cc < 2; ++cc)
#pragma unroll
          for (int r = 0; r < 16; ++r)
            st[cc][r] = __builtin_amdgcn_exp2f(st[cc][r] - mrow);

        unsigned int pk[2][4], pk2[2][4];
#pragma unroll
        for (int cc = 0; cc < 2; ++cc)
#pragma unroll
          for (int g = 0; g < 4; ++g) {
            pk[cc][g]  = cvt_pk_bf16(st[cc][4 * g + 0], st[cc][4 * g + 1]);
            pk2[cc][g] = cvt_pk_bf16(st[cc][4 * g + 2], st[cc][4 * g + 3]);
          }

        __builtin_amdgcn_s_setprio(1);
#pragma unroll
        for (int ks = 0; ks < 4; ++ks) {
          const int cc = ks >> 1, g0 = 2 * (ks & 1), g1 = g0 + 1;
          unsigned int Aw = pk[cc][g0], Bw = pk[cc][g1];
          asm volatile("v_permlane32_swap_b32 %0, %1" : "+v"(Aw), "+v"(Bw));
          unsigned int A2 = pk2[cc][g0], B2 = pk2[cc][g1];
          asm volatile("v_permlane32_swap_b32 %0, %1" : "+v"(A2), "+v"(B2));
          union { unsigned int u[4]; bf16x8 v; } pb;
          pb.u[0] = Aw; pb.u[1] = A2; pb.u[2] = Bw; pb.u[3] = B2;
          lsum = __builtin_amdgcn_mfma_f32_32x32x16_bf16(vones, pb.v, lsum, 0, 0, 0);
#pragma unroll
          for (int dc = 0; dc < 2; ++dc) {
            bf16x8 vf = *reinterpret_cast<const bf16x8*>(
                vb + (dc * 32 + l31) * 64 + (((ks * 2 + hi) ^ (l31 & 7)) * 8));
            ot[dc] = __builtin_amdgcn_mfma_f32_32x32x16_bf16(vf, pb.v, ot[dc], 0, 0, 0);
          }
        }
        __builtin_amdgcn_s_setprio(0);
      }

      __syncthreads();
      buf ^= 1;
    }

    const float inv = 1.0f / lsum[0];
    __bf16* aout = (__bf16*)attn_out + (size_t)(b * SS + qq) * DD + h * DKK;
#pragma unroll
    for (int dc = 0; dc < 2; ++dc)
#pragma unroll
      for (int g = 0; g < 4; ++g) {
        uint2 pw;
        pw.x = cvt_pk_bf16(ot[dc][4 * g + 0] * inv, ot[dc][4 * g + 1] * inv);
        pw.y = cvt_pk_bf16(ot[dc][4 * g + 2] * inv, ot[dc][4 * g + 3] * inv);
        *reinterpret_cast<uint2*>(aout + dc * 32 + 4 * hi + 8 * g) = pw;
      }
  };

  process(NQT - 1 - pi);
  process(pi);
}

// ---------------- launch ----------------
extern "C" void kernel_launch(void* const* d_in, const int* in_sizes, int n_in,
                              void* d_out, int out_size, void* d_ws, size_t ws_size,
                              hipStream_t stream) {
  const float* x = (const float*)d_in[0];
  const float* w_q = (const float*)d_in[1];
  const float* w_k = (const float*)d_in[2];
  const float* w_v = (const float*)d_in[3];
  const float* w_o = (const float*)d_in[4];
  const float* b_o = (const float*)d_in[5];
  float* out = (float*)d_out;

  unsigned short* ws = (unsigned short*)d_ws;
  unsigned short* x_bf = ws;                               // 8192*1024
  unsigned short* w_qkv = x_bf + (size_t)MM * DD;          // 3072*1024
  unsigned short* w_obf = w_qkv + (size_t)NQKV * DD;       // 1024*1024
  unsigned short* qkv = w_obf + (size_t)DD * DD;           // 8192*3072 (V region unused)
  unsigned short* vt = qkv + (size_t)MM * NQKV;            // B*H*DK*S = 8388608
  unsigned short* attn = vt + (size_t)BB * HH * DKK * SS;  // 8192*1024

  // converts
  cvt_kernel<<<(MM * DD / 4 + 255) / 256, 256, 0, stream>>>(x, (__bf16*)x_bf, MM * DD / 4);
  cvtw_kernel<<<dim3(DD * DD / 4 / 256, 4), 256, 0, stream>>>(w_q, w_k, w_v, w_o,
                                                              (__bf16*)w_qkv, (__bf16*)w_obf);

  // QKV projection (m97-style 128^2, 3 blocks/CU; Q prescaled; V -> vt transposed)
  gemm128<2><<<dim3(NQKV / 128, MM / 128), 256, 0, stream>>>(x_bf, w_qkv, qkv, nullptr, vt, NQKV, DD);

  // attention (pair-balanced causal schedule)
  attn_kernel<<<dim3(NQT / 2, HH, BB), 256, 0, stream>>>(qkv, vt, attn);

  // output projection: [8192,1024] = attn @ w_o^T + b_o
  gemm128<0><<<dim3(DD / 128, MM / 128), 256, 0, stream>>>(attn, w_obf, out, b_o, nullptr, DD, DD);
}